// Round 8
// baseline (212.358 us; speedup 1.0000x reference)
//
#include <hip/hip_runtime.h>

#define S_LEN 4096
#define HIDDEN 1024
#define NH 8
#define NKV 2
#define HD 128
#define WIN 2048

typedef short bf16x8 __attribute__((ext_vector_type(8)));
typedef short bf16x4 __attribute__((ext_vector_type(4)));
typedef float f32x4 __attribute__((ext_vector_type(4)));
typedef unsigned short u16x4 __attribute__((ext_vector_type(4)));

__device__ __forceinline__ unsigned short f2b(float f) {
    unsigned int u = __builtin_bit_cast(unsigned int, f);
    u += 0x7fffu + ((u >> 16) & 1u);     // round-to-nearest-even
    return (unsigned short)(u >> 16);
}
__device__ __forceinline__ float b2f(unsigned short u) {
    unsigned int x = ((unsigned int)u) << 16;
    return __builtin_bit_cast(float, x);
}

// async global->LDS, 16B per lane, lands at ldsbase + lane*16 (wave-uniform base)
__device__ __forceinline__ void gl_lds16(const unsigned short* g, unsigned short* l) {
    __builtin_amdgcn_global_load_lds(
        (const __attribute__((address_space(1))) unsigned int*)g,
        (__attribute__((address_space(3))) unsigned int*)l, 16, 0, 0);
}

// s_waitcnt immediates (gfx9): vmcnt[3:0]|[15:14], exp[6:4], lgkm[11:8]
#define WAIT_VM6   0x0F76   // vmcnt<=6
#define WAIT_VM0   0x0F70   // vmcnt==0
#define MEMFENCE() __asm__ volatile("" ::: "memory")

#define NSPLIT_QT 47        // qt 17..63 are split (nch >= 18)

// ---------------------------------------------------------------------------
// One-shot fp32 -> bf16 of the five input tensors (float4 granularity).
// (R25 post-mortem: nontemporal stores REGRESSED +10us — NT evicts to HBM,
//  consumers re-fetch from HBM instead of LLC.  Plain stores restored.)
// ---------------------------------------------------------------------------
__global__ __launch_bounds__(256) void cvt5(
    const float* __restrict__ s0, unsigned short* __restrict__ t0, int n0,
    const float* __restrict__ s1, unsigned short* __restrict__ t1, int n1,
    const float* __restrict__ s2, unsigned short* __restrict__ t2, int n2,
    const float* __restrict__ s3, unsigned short* __restrict__ t3, int n3,
    const float* __restrict__ s4, unsigned short* __restrict__ t4, int n4)
{
    int i = blockIdx.x * 256 + threadIdx.x;   // float4 index
    const float* s; unsigned short* t;
    if (i < n0)              { s = s0; t = t0; }
    else if ((i -= n0) < n1) { s = s1; t = t1; }
    else if ((i -= n1) < n2) { s = s2; t = t2; }
    else if ((i -= n2) < n3) { s = s3; t = t3; }
    else if ((i -= n3) < n4) { s = s4; t = t4; }
    else return;
    f32x4 v = *(const f32x4*)(s + (size_t)i * 4);
    u16x4 r = { f2b(v[0]), f2b(v[1]), f2b(v[2]), f2b(v[3]) };
    *(u16x4*)(t + (size_t)i * 4) = r;
}

// ---------------------------------------------------------------------------
// Output projection GEMM, tile 64x128 (R20 config — best measured: 180.8).
// 16 phases x {wait vm6, barrier, stage 2 slices, 16 MFMA}, SIX 32-K LDS
// slice buffers.  s_setprio(1) wraps each 8-MFMA cluster.
// ---------------------------------------------------------------------------
__global__ __launch_bounds__(256, 2) void gemm128(
    const unsigned short* __restrict__ A, const unsigned short* __restrict__ W,
    float* __restrict__ Cf, unsigned short* __restrict__ Cb,
    int M, int N, int K)
{
    __shared__ alignas(16) unsigned short As[6][64 * 32];    // 24 KB
    __shared__ alignas(16) unsigned short Bs[6][128 * 32];   // 48 KB

    int lane = threadIdx.x & 63;
    int w = threadIdx.x >> 6;
    int l15 = lane & 15, quad = lane >> 4;

    int tiles_n = N >> 7;
    int bid = (int)blockIdx.x;
    int nb = (int)gridDim.x;
    int lb = bid;
    if ((nb & 7) == 0) {                 // bijective XCD-chunk swizzle
        int c = nb >> 3;
        lb = (bid & 7) * c + (bid >> 3);
    }
    int mt0 = lb / tiles_n;
    int nt0 = lb - mt0 * tiles_n;

    size_t goffA;
    {
        int s = w * 64 + lane;
        int row = s >> 2, spos = s & 3;
        int kblk = spos ^ ((row >> 1) & 3);
        goffA = (size_t)(mt0 * 64 + row) * K + kblk * 8;
    }
    size_t goffB[2];
    #pragma unroll
    for (int is = 0; is < 2; ++is) {
        int s = w * 128 + is * 64 + lane;
        int row = s >> 2, spos = s & 3;
        int kblk = spos ^ ((row >> 1) & 3);
        goffB[is] = (size_t)(nt0 * 128 + row) * K + kblk * 8;
    }

    int arow0 = (w >> 1) * 32;
    int brow0 = (w & 1) * 64;
    int aoff[2], boff[4];
    #pragma unroll
    for (int t = 0; t < 2; ++t) {
        int ra = arow0 + t * 16 + l15;
        aoff[t] = (ra * 4 + (quad ^ ((ra >> 1) & 3))) * 8;
    }
    #pragma unroll
    for (int j = 0; j < 4; ++j) {
        int rb = brow0 + j * 16 + l15;
        boff[j] = (rb * 4 + (quad ^ ((rb >> 1) & 3))) * 8;
    }

    f32x4 acc[2][4];
    #pragma unroll
    for (int i = 0; i < 2; ++i)
        #pragma unroll
        for (int j = 0; j < 4; ++j) acc[i][j] = (f32x4){0.f, 0.f, 0.f, 0.f};

    auto stage = [&](int s, int b) {
        int k0 = s * 32;
        gl_lds16(A + goffA + k0, &As[b][(w * 64) * 8]);
        gl_lds16(W + goffB[0] + k0, &Bs[b][(w * 128 + 0) * 8]);
        gl_lds16(W + goffB[1] + k0, &Bs[b][(w * 128 + 64) * 8]);
    };

    int nk = K >> 5;            // 32 slices (K=1024); nk even required
    int np = nk >> 1;           // 16 phases
    if (nk > 0) stage(0, 0);
    if (nk > 1) stage(1, 1);
    if (nk > 2) stage(2, 2);
    if (nk > 3) stage(3, 3);
    int cb = 0, sb = 4;
    for (int j = 0; j < np; ++j) {
        MEMFENCE();
        if (j + 1 < np) __builtin_amdgcn_s_waitcnt(WAIT_VM6);
        else            __builtin_amdgcn_s_waitcnt(WAIT_VM0);
        __builtin_amdgcn_s_barrier();
        MEMFENCE();
        int s0 = 2 * j + 4;
        if (s0 < nk)     stage(s0, sb);
        if (s0 + 1 < nk) stage(s0 + 1, sb + 1 == 6 ? 0 : sb + 1);
        sb += 2; if (sb >= 6) sb -= 6;

        #pragma unroll
        for (int half = 0; half < 2; ++half) {
            const unsigned short* Ab = &As[cb + half][0];
            const unsigned short* Bb = &Bs[cb + half][0];
            bf16x8 af[2], bf_[4];
            #pragma unroll
            for (int t = 0; t < 2; ++t) af[t]  = *(const bf16x8*)(Ab + aoff[t]);
            #pragma unroll
            for (int jj = 0; jj < 4; ++jj) bf_[jj] = *(const bf16x8*)(Bb + boff[jj]);
            __builtin_amdgcn_s_setprio(1);
            #pragma unroll
            for (int i2 = 0; i2 < 2; ++i2)
                #pragma unroll
                for (int jj = 0; jj < 4; ++jj)
                    acc[i2][jj] = __builtin_amdgcn_mfma_f32_16x16x32_bf16(af[i2], bf_[jj], acc[i2][jj], 0, 0, 0);
            __builtin_amdgcn_s_setprio(0);
        }
        cb += 2; if (cb >= 6) cb -= 6;
        MEMFENCE();
    }

    #pragma unroll
    for (int i = 0; i < 2; ++i) {
        int row0 = mt0 * 64 + arow0 + i * 16 + quad * 4;
        #pragma unroll
        for (int j = 0; j < 4; ++j) {
            int col = nt0 * 128 + brow0 + j * 16 + l15;
            if (Cf) {
                #pragma unroll
                for (int reg = 0; reg < 4; ++reg)
                    Cf[(size_t)(row0 + reg) * N + col] = acc[i][j][reg];
            } else {
                #pragma unroll
                for (int reg = 0; reg < 4; ++reg)
                    Cb[(size_t)(row0 + reg) * N + col] = f2b(acc[i][j][reg]);
            }
        }
    }
}

// ---------------------------------------------------------------------------
// QKV projection, tile 64x128, 2-slice phases + 6 slice buffers (R20 config).
// FUSED epilogues: nt0 0..7 = Q (rope+prescale), 8..9 = K (rope), 10..11 =
// V (transpose).  Staging pool aliased with Ex/T epilogue LDS.
// ---------------------------------------------------------------------------
#define QKVW (HIDDEN + 2 * NKV * HD)   // 1536
__global__ __launch_bounds__(256, 2) void gemmqkv(
    const unsigned short* __restrict__ A, const unsigned short* __restrict__ W,
    const int* __restrict__ pos,
    unsigned short* __restrict__ Qb, unsigned short* __restrict__ Kb,
    unsigned short* __restrict__ Vt)
{
    __shared__ alignas(16) char pool[73728];   // 72 KB
    unsigned short (*As)[64 * 32]  = (unsigned short (*)[64 * 32])(pool);           // 6 x 4 KB
    unsigned short (*Bs)[128 * 32] = (unsigned short (*)[128 * 32])(pool + 24576);  // 6 x 8 KB
    float (*Ex)[32][68] = (float (*)[32][68])(pool);     // 34.8 KB (epilogue alias)
    unsigned short* T = (unsigned short*)(pool);         // 16.6 KB (epilogue alias)

    int lane = threadIdx.x & 63;
    int w = threadIdx.x >> 6;
    int l15 = lane & 15, quad = lane >> 4;

    const int K = HIDDEN;
    int bid = (int)blockIdx.x;
    int lb = (bid & 7) * 96 + (bid >> 3);    // bijective: 768 = 8 * 96
    int mt0 = lb / 12;
    int nt0 = lb - mt0 * 12;

    size_t goffA;
    {
        int s = w * 64 + lane;
        int row = s >> 2, spos = s & 3;
        int kblk = spos ^ ((row >> 1) & 3);
        goffA = (size_t)(mt0 * 64 + row) * K + kblk * 8;
    }
    size_t goffB[2];
    #pragma unroll
    for (int is = 0; is < 2; ++is) {
        int s = w * 128 + is * 64 + lane;
        int row = s >> 2, spos = s & 3;
        int kblk = spos ^ ((row >> 1) & 3);
        goffB[is] = (size_t)(nt0 * 128 + row) * K + kblk * 8;
    }

    int arow0 = (w >> 1) * 32;
    int brow0 = (w & 1) * 64;
    int aoff[2], boff[4];
    #pragma unroll
    for (int t = 0; t < 2; ++t) {
        int ra = arow0 + t * 16 + l15;
        aoff[t] = (ra * 4 + (quad ^ ((ra >> 1) & 3))) * 8;
    }
    #pragma unroll
    for (int j = 0; j < 4; ++j) {
        int rb = brow0 + j * 16 + l15;
        boff[j] = (rb * 4 + (quad ^ ((rb >> 1) & 3))) * 8;
    }

    f32x4 acc[2][4];
    #pragma unroll
    for (int i = 0; i < 2; ++i)
        #pragma unroll
        for (int j = 0; j < 4; ++j) acc[i][j] = (f32x4){0.f, 0.f, 0.f, 0.f};

    auto stage = [&](int s, int b) {
        int k0 = s * 32;
        gl_lds16(A + goffA + k0, &As[b][(w * 64) * 8]);
        gl_lds16(W + goffB[0] + k0, &Bs[b][(w * 128 + 0) * 8]);
        gl_lds16(W + goffB[1] + k0, &Bs[b][(w * 128 + 64) * 8]);
    };

    stage(0, 0);
    stage(1, 1);
    stage(2, 2);
    stage(3, 3);
    int cb = 0, sb = 4;
    for (int j = 0; j < 16; ++j) {
        MEMFENCE();
        if (j < 15) __builtin_amdgcn_s_waitcnt(WAIT_VM6);
        else        __builtin_amdgcn_s_waitcnt(WAIT_VM0);
        __builtin_amdgcn_s_barrier();
        MEMFENCE();
        int s0 = 2 * j + 4;
        if (s0 < 32)     stage(s0, sb);
        if (s0 + 1 < 32) stage(s0 + 1, sb + 1 == 6 ? 0 : sb + 1);
        sb += 2; if (sb >= 6) sb -= 6;

        #pragma unroll
        for (int half = 0; half < 2; ++half) {
            const unsigned short* Ab = &As[cb + half][0];
            const unsigned short* Bb = &Bs[cb + half][0];
            bf16x8 af[2], bf_[4];
            #pragma unroll
            for (int t = 0; t < 2; ++t) af[t]  = *(const bf16x8*)(Ab + aoff[t]);
            #pragma unroll
            for (int jj = 0; jj < 4; ++jj) bf_[jj] = *(const bf16x8*)(Bb + boff[jj]);
            __builtin_amdgcn_s_setprio(1);
            #pragma unroll
            for (int i2 = 0; i2 < 2; ++i2)
                #pragma unroll
                for (int jj = 0; jj < 4; ++jj)
                    acc[i2][jj] = __builtin_amdgcn_mfma_f32_16x16x32_bf16(af[i2], bf_[jj], acc[i2][jj], 0, 0, 0);
            __builtin_amdgcn_s_setprio(0);
        }
        cb += 2; if (cb >= 6) cb -= 6;
        MEMFENCE();
    }

    if (nt0 >= 10) {
        // ---- V: bf16 -> LDS tile [64 s][130 d-stride] -> transposed Vt
        int kv = nt0 - 10;
        __syncthreads();   // all K-loop LDS reads done before pool reuse
        #pragma unroll
        for (int i = 0; i < 2; ++i) {
            int srow = arow0 + i * 16 + quad * 4;
            #pragma unroll
            for (int j = 0; j < 4; ++j) {
                int d = brow0 + j * 16 + l15;
                #pragma unroll
                for (int reg = 0; reg < 4; ++reg)
                    T[(srow + reg) * 130 + d] = f2b(acc[i][j][reg]);
            }
        }
        __syncthreads();
        int tid = threadIdx.x;
        int dl = tid >> 4;               // 0..15
        int s4 = (tid & 15) * 4;         // s chunk (0..60)
        #pragma unroll
        for (int it = 0; it < 8; ++it) {
            int d = it * 16 + dl;
            u16x4 v4 = { T[(s4 + 0) * 130 + d], T[(s4 + 1) * 130 + d],
                         T[(s4 + 2) * 130 + d], T[(s4 + 3) * 130 + d] };
            *(u16x4*)(Vt + (size_t)kv * HD * S_LEN + (size_t)d * S_LEN
                      + mt0 * 64 + s4) = v4;
        }
        return;
    }

    // ---- Q/K: rope epilogue (one exchange round)
    bool isQ = (nt0 < 8);
    int kv = nt0 - 8;
    bool is64 = (pos[1] == 0) && (pos[3] == 0);
    const float qscale = 0.08838834764831843f;

    float invf[4];
    #pragma unroll
    for (int j = 0; j < 4; ++j) {
        int d6 = (brow0 + j * 16 + l15) & 63;
        invf[j] = exp2f(-(float)d6 * (13.287712379549449f / 64.0f));
    }

    __syncthreads();   // K-loop LDS reads done before pool reuse
    #pragma unroll
    for (int i = 0; i < 2; ++i)
        #pragma unroll
        for (int j = 0; j < 4; ++j)
            #pragma unroll
            for (int reg = 0; reg < 4; ++reg)
                Ex[w][i * 16 + quad * 4 + reg][j * 16 + l15] = acc[i][j][reg];
    __syncthreads();
    #pragma unroll
    for (int i = 0; i < 2; ++i) {
        #pragma unroll
        for (int reg = 0; reg < 4; ++reg) {
            int s = mt0 * 64 + arow0 + i * 16 + quad * 4 + reg;
            int pv_ = is64 ? pos[2 * s] : pos[s];
            float pf = (float)pv_;
            #pragma unroll
            for (int j = 0; j < 4; ++j) {
                float sn, cs;
                __sincosf(pf * invf[j], &sn, &cs);
                float a  = acc[i][j][reg];
                float pr = Ex[w ^ 1][i * 16 + quad * 4 + reg][j * 16 + l15];
                int d_local = brow0 + j * 16 + l15;
                float outv = (d_local < 64) ? (a * cs - pr * sn) : (a * cs + pr * sn);
                if (isQ) {
                    Qb[(size_t)s * HIDDEN + nt0 * HD + d_local] = f2b(outv * qscale);
                } else {
                    Kb[(size_t)kv * S_LEN * HD + (size_t)s * HD + d_local] = f2b(outv);
                }
            }
        }
    }
}

// ---------------------------------------------------------------------------
// Flash attention — R26: SPLIT-K load balancing.  Static schedule was
// makespan-bound: per-(qt,h) chunk counts nch = min(qt+1,33), paired CU
// sums 34..65 units vs 49.5 avg -> 66us at ~1us/unit, and 33-unit blocks
// mean NO static pairing beats 50.  This kernel uses plain exp (no online
// max), so partial (O,l) over disjoint chunk ranges combine by PURE
// ADDITION.  Grid (64,8,2): nch>17 tiles split into halves of <=17 chunks;
// each half writes f32 partials, fences, atomicAdd a pair counter; the
// SECOND arriver combines (f32 add commutative -> bit-identical output
// regardless of arrival order) and writes Ctx.  No spin, no co-residency
// assumption.  Inner chunk loop bit-identical to the frozen R20 body.
// ---------------------------------------------------------------------------
__global__ __launch_bounds__(256, 2) void attn_coop(
    const unsigned short* __restrict__ Qb, const unsigned short* __restrict__ Kb,
    const unsigned short* __restrict__ Vt, unsigned short* __restrict__ Ctx,
    float* __restrict__ Po, float* __restrict__ Pl, unsigned int* __restrict__ cnt)
{
    __shared__ alignas(16) unsigned short Klds[2][64 * 128];   // 32 KB
    __shared__ alignas(16) unsigned short Vlds[2][128 * 64];   // 32 KB
    __shared__ unsigned int oldv;

    int lane = threadIdx.x & 63;
    int w = threadIdx.x >> 6;
    int l15 = lane & 15, quad = lane >> 4;
    int h = blockIdx.y;
    int z = (int)blockIdx.z;
    int kv = h >> 2;                 // GROUPS = 4
    int qt = (h & 4) ? (63 - (int)blockIdx.x) : (int)blockIdx.x;
    int qb = qt * 64;
    int q16 = qb + w * 16;

    int lo = qb - (WIN - 1); if (lo < 0) lo = 0; lo &= ~63;
    int nch = (qb + 64 - lo) >> 6;   // <= 33

    bool split = nch > 17;           // qt >= 17
    if (!split && z) return;         // light tiles: single block (z=0)
    int cbeg = (split && z) ? (nch >> 1) : 0;
    int cend = (split && !z) ? (nch >> 1) : nch;

    bf16x8 a_q[4];
    const unsigned short* qrow = Qb + (size_t)(q16 + l15) * HIDDEN + h * HD + quad * 8;
    #pragma unroll
    for (int st = 0; st < 4; ++st) a_q[st] = *(const bf16x8*)(qrow + st * 32);

    bf16x4 ones4;
    #pragma unroll
    for (int i = 0; i < 4; ++i) ones4[i] = (short)0x3F80;   // bf16 1.0

    const unsigned short* gbase;
    unsigned short* ldsdst[2];
    int myoff[8];
    int jmul;
    if (w < 2) {
        gbase = Kb + (size_t)kv * S_LEN * HD;
        ldsdst[0] = &Klds[0][w * 8 * 512];
        ldsdst[1] = &Klds[1][w * 8 * 512];
        jmul = HD;
        #pragma unroll
        for (int tt = 0; tt < 8; ++tt) {
            int t = w * 8 + tt;
            int key  = t * 4 + (lane >> 4);
            int dblk = (lane & 15) ^ (key & 15);
            myoff[tt] = key * HD + dblk * 8;
        }
    } else {
        gbase = Vt + (size_t)kv * HD * S_LEN;
        ldsdst[0] = &Vlds[0][(w - 2) * 8 * 512];
        ldsdst[1] = &Vlds[1][(w - 2) * 8 * 512];
        jmul = 1;
        #pragma unroll
        for (int tt = 0; tt < 8; ++tt) {
            int t = (w - 2) * 8 + tt;
            int d    = t * 8 + (lane >> 3);
            int kblk = (lane & 7) ^ (d & 7);
            myoff[tt] = d * S_LEN + kblk * 8;
        }
    }

    auto issue = [&](int c) {
        int j0 = lo + c * 64;
        const unsigned short* src = gbase + (size_t)j0 * jmul;
        unsigned short* dst = ldsdst[c & 1];
        #pragma unroll
        for (int tt = 0; tt < 8; ++tt)
            gl_lds16(src + myoff[tt], dst + tt * 512);
    };

    f32x4 o[9];                      // o[0..7] = d-tiles, o[8] = row-sums l
    #pragma unroll
    for (int nd = 0; nd < 9; ++nd) o[nd] = (f32x4){0.f, 0.f, 0.f, 0.f};

    issue(cbeg);

    for (int c = cbeg; c < cend; ++c) {
        int j0 = lo + c * 64;

        MEMFENCE();
        __builtin_amdgcn_s_waitcnt(WAIT_VM0);   // my slice of chunk c landed
        __builtin_amdgcn_s_barrier();           // chunk staged; buf[c-1] drained
        MEMFENCE();
        if (c + 1 < cend) issue(c + 1);

        const unsigned short* Kc = &Klds[c & 1][0];
        const unsigned short* Vc = &Vlds[c & 1][0];

        // ---- S^T tiles: [16 keys x 16 queries], A = K-frag, B = Q-frag
        f32x4 sc[4];
        #pragma unroll
        for (int t = 0; t < 4; ++t) {
            sc[t] = (f32x4){0.f, 0.f, 0.f, 0.f};
            int key = t * 16 + l15;
            #pragma unroll
            for (int st = 0; st < 4; ++st) {
                int off16 = key * 16 + ((st * 4 + quad) ^ (key & 15));
                bf16x8 ak = *(const bf16x8*)(Kc + off16 * 8);
                sc[t] = __builtin_amdgcn_mfma_f32_16x16x32_bf16(ak, a_q[st], sc[t], 0, 0, 0);
            }
        }

        // ---- P^T = exp(S^T): row = key (quad*4+reg), col = query (l15)
        float p[4][4];
        if (j0 + 63 <= q16 && j0 > q16 + 15 - WIN) {
            #pragma unroll
            for (int t = 0; t < 4; ++t)
                #pragma unroll
                for (int reg = 0; reg < 4; ++reg) p[t][reg] = __expf(sc[t][reg]);
        } else {
            int iq = q16 + l15;
            #pragma unroll
            for (int t = 0; t < 4; ++t) {
                #pragma unroll
                for (int reg = 0; reg < 4; ++reg) {
                    int key = j0 + t * 16 + quad * 4 + reg;
                    p[t][reg] = (key <= iq && key > iq - WIN) ? __expf(sc[t][reg]) : 0.f;
                }
            }
        }

        // ---- pack P into K=16 A-fragments — no LDS round-trip
        bf16x4 a_p[4];
        #pragma unroll
        for (int t = 0; t < 4; ++t) {
            a_p[t][0] = (short)f2b(p[t][0]);
            a_p[t][1] = (short)f2b(p[t][1]);
            a_p[t][2] = (short)f2b(p[t][2]);
            a_p[t][3] = (short)f2b(p[t][3]);
        }

        // ---- O += P@V, l += P@1 : 4 key-groups x (8 d-tiles + 1), K=16
        #pragma unroll
        for (int t = 0; t < 4; ++t) {
            #pragma unroll
            for (int nd = 0; nd < 8; ++nd) {
                int d = nd * 16 + l15;
                int kblk = t * 2 + (quad >> 1);
                int slot = d * 8 + (kblk ^ (d & 7));
                bf16x4 bv = *(const bf16x4*)(Vc + slot * 8 + (quad & 1) * 4);
                o[nd] = __builtin_amdgcn_mfma_f32_16x16x16bf16_1k(a_p[t], bv, o[nd], 0, 0, 0);
            }
            o[8] = __builtin_amdgcn_mfma_f32_16x16x16bf16_1k(a_p[t], ones4, o[8], 0, 0, 0);
        }
        MEMFENCE();
    }

    if (!split) {
        // ---- direct epilogue: ctx = O / l (col=l15=d, row=quad*4+reg=q)
        #pragma unroll
        for (int nd = 0; nd < 8; ++nd) {
            int d = nd * 16 + l15;
            #pragma unroll
            for (int reg = 0; reg < 4; ++reg) {
                int q = q16 + quad * 4 + reg;
                Ctx[(size_t)q * HIDDEN + h * HD + d] = f2b(o[nd][reg] / o[8][reg]);
            }
        }
        return;
    }

    // ---- split epilogue: write partials, second arriver combines
    int pidx = (qt - 17) * 8 + h;
    size_t mybase = (size_t)(pidx * 2 + z) * 64;
    #pragma unroll
    for (int nd = 0; nd < 8; ++nd) {
        int d = nd * 16 + l15;
        #pragma unroll
        for (int reg = 0; reg < 4; ++reg) {
            int ql = w * 16 + quad * 4 + reg;
            Po[(mybase + ql) * 128 + d] = o[nd][reg];
        }
    }
    if (l15 == 0) {
        #pragma unroll
        for (int reg = 0; reg < 4; ++reg) {
            int ql = w * 16 + quad * 4 + reg;
            Pl[mybase + ql] = o[8][reg];
        }
    }
    __syncthreads();                       // all stores drained to L2
    if (threadIdx.x == 0) {
        __threadfence();                   // release: L2 -> LLC
        oldv = atomicAdd(&cnt[pidx], 1u);  // device-scope arrival
    }
    __syncthreads();
    if (oldv == 0) return;                 // first arriver leaves partials
    if (threadIdx.x == 0) __threadfence(); // acquire: invalidate stale lines
    __syncthreads();

    size_t pbase = (size_t)(pidx * 2 + (z ^ 1)) * 64;
    float lp[4];
    #pragma unroll
    for (int reg = 0; reg < 4; ++reg) {
        int ql = w * 16 + quad * 4 + reg;
        lp[reg] = Pl[pbase + ql];
    }
    #pragma unroll
    for (int nd = 0; nd < 8; ++nd) {
        int d = nd * 16 + l15;
        #pragma unroll
        for (int reg = 0; reg < 4; ++reg) {
            int ql = w * 16 + quad * 4 + reg;
            float po = Po[(pbase + ql) * 128 + d];
            int q = q16 + quad * 4 + reg;
            Ctx[(size_t)q * HIDDEN + h * HD + d] =
                f2b((o[nd][reg] + po) / (o[8][reg] + lp[reg]));
        }
    }
}

// ---------------------------------------------------------------------------
extern "C" void kernel_launch(void* const* d_in, const int* in_sizes, int n_in,
                              void* d_out, int out_size, void* d_ws, size_t ws_size,
                              hipStream_t stream)
{
    const float* hidden = (const float*)d_in[0];
    const float* wq = (const float*)d_in[1];
    const float* wk = (const float*)d_in[2];
    const float* wv = (const float*)d_in[3];
    const float* wo = (const float*)d_in[4];
    const int* pos = (const int*)d_in[5];
    float* out = (float*)d_out;

    char* ws = (char*)d_ws;
    size_t off = 0;
    unsigned short* Hb   = (unsigned short*)(ws + off); off += (size_t)S_LEN * HIDDEN * 2;
    unsigned short* Wqkv = (unsigned short*)(ws + off); off += (size_t)QKVW * HIDDEN * 2;
    unsigned short* Wob  = (unsigned short*)(ws + off); off += (size_t)HIDDEN * HIDDEN * 2;
    unsigned short* Qb   = (unsigned short*)(ws + off); off += (size_t)S_LEN * HIDDEN * 2;
    unsigned short* Kb   = (unsigned short*)(ws + off); off += (size_t)S_LEN * NKV * HD * 2;
    unsigned short* Vt   = (unsigned short*)(ws + off); off += (size_t)S_LEN * NKV * HD * 2;
    unsigned short* Cb   = (unsigned short*)(ws + off); off += (size_t)S_LEN * HIDDEN * 2;
    float* Po            = (float*)(ws + off);          off += (size_t)NSPLIT_QT * 8 * 2 * 64 * 128 * 4;
    float* Pl            = (float*)(ws + off);          off += (size_t)NSPLIT_QT * 8 * 2 * 64 * 4;
    unsigned int* cnt    = (unsigned int*)(ws + off);   off += 2048;

    // zero split-pair arrival counters each replay (graph-capturable)
    hipMemsetAsync(cnt, 0, NSPLIT_QT * 8 * sizeof(unsigned int), stream);

    const int n_h  = S_LEN * HIDDEN / 4;
    const int n_wq = HIDDEN * HIDDEN / 4;
    const int n_wk = NKV * HD * HIDDEN / 4;
    int tot4 = n_h + n_wq + 2 * n_wk + n_wq;
    cvt5<<<(tot4 + 255) / 256, 256, 0, stream>>>(
        hidden, Hb, n_h,
        wq, Wqkv, n_wq,
        wk, Wqkv + (size_t)HIDDEN * HIDDEN, n_wk,
        wv, Wqkv + (size_t)(HIDDEN + NKV * HD) * HIDDEN, n_wk,
        wo, Wob, n_wq);

    // fused QKV projection + RoPE + V-transpose, 64x128 tiles (768 blocks)
    gemmqkv<<<(S_LEN / 64) * 12, 256, 0, stream>>>(
        Hb, Wqkv, pos, Qb, Kb, Vt);

    // flash attention, split-K (1024 blocks, <=17 chunks each)
    attn_coop<<<dim3(S_LEN / 64, NH, 2), 256, 0, stream>>>(
        Qb, Kb, Vt, Cb, Po, Pl, cnt);

    // output projection -> fp32 d_out, 64x128 tiles (512 blocks)
    gemm128<<<(S_LEN / 64) * (HIDDEN / 128), 256, 0, stream>>>(
        Cb, Wob, out, nullptr, S_LEN, HIDDEN, HIDDEN);
}

// Round 9
// 179.534 us; speedup vs baseline: 1.1828x; 1.1828x over previous
//
#include <hip/hip_runtime.h>

#define S_LEN 4096
#define HIDDEN 1024
#define NH 8
#define NKV 2
#define HD 128
#define WIN 2048

typedef short bf16x8 __attribute__((ext_vector_type(8)));
typedef short bf16x4 __attribute__((ext_vector_type(4)));
typedef float f32x4 __attribute__((ext_vector_type(4)));
typedef unsigned short u16x4 __attribute__((ext_vector_type(4)));

__device__ __forceinline__ unsigned short f2b(float f) {
    unsigned int u = __builtin_bit_cast(unsigned int, f);
    u += 0x7fffu + ((u >> 16) & 1u);     // round-to-nearest-even
    return (unsigned short)(u >> 16);
}
__device__ __forceinline__ float b2f(unsigned short u) {
    unsigned int x = ((unsigned int)u) << 16;
    return __builtin_bit_cast(float, x);
}

// async global->LDS, 16B per lane, lands at ldsbase + lane*16 (wave-uniform base)
__device__ __forceinline__ void gl_lds16(const unsigned short* g, unsigned short* l) {
    __builtin_amdgcn_global_load_lds(
        (const __attribute__((address_space(1))) unsigned int*)g,
        (__attribute__((address_space(3))) unsigned int*)l, 16, 0, 0);
}

// s_waitcnt immediates (gfx9): vmcnt[3:0]|[15:14], exp[6:4], lgkm[11:8]
#define WAIT_VM6   0x0F76   // vmcnt<=6
#define WAIT_VM0   0x0F70   // vmcnt==0
#define MEMFENCE() __asm__ volatile("" ::: "memory")

// ---------------------------------------------------------------------------
// One-shot fp32 -> bf16 of the five input tensors (float4 granularity).
// Plain stores (R25: nontemporal regressed +10us — NT evicts to HBM).
// ---------------------------------------------------------------------------
__global__ __launch_bounds__(256) void cvt5(
    const float* __restrict__ s0, unsigned short* __restrict__ t0, int n0,
    const float* __restrict__ s1, unsigned short* __restrict__ t1, int n1,
    const float* __restrict__ s2, unsigned short* __restrict__ t2, int n2,
    const float* __restrict__ s3, unsigned short* __restrict__ t3, int n3,
    const float* __restrict__ s4, unsigned short* __restrict__ t4, int n4)
{
    int i = blockIdx.x * 256 + threadIdx.x;   // float4 index
    const float* s; unsigned short* t;
    if (i < n0)              { s = s0; t = t0; }
    else if ((i -= n0) < n1) { s = s1; t = t1; }
    else if ((i -= n1) < n2) { s = s2; t = t2; }
    else if ((i -= n2) < n3) { s = s3; t = t3; }
    else if ((i -= n3) < n4) { s = s4; t = t4; }
    else return;
    f32x4 v = *(const f32x4*)(s + (size_t)i * 4);
    u16x4 r = { f2b(v[0]), f2b(v[1]), f2b(v[2]), f2b(v[3]) };
    *(u16x4*)(t + (size_t)i * 4) = r;
}

// ---------------------------------------------------------------------------
// Output projection GEMM, tile 64x128 (R20 config — best measured: 180.8).
// 16 phases x {wait vm6, barrier, stage 2 slices, 16 MFMA}, SIX 32-K LDS
// slice buffers.  s_setprio(1) wraps each 8-MFMA cluster.
// Post-mortems: 128^2 tile worse (R21, latency-chain-bound, fewer blocks);
// NT stores worse (R25); kernel fusion worse (R24, grid-barrier spin);
// attn split-K worse (R26, partial traffic to HBM).  This is the floor
// configuration for this harness.
// ---------------------------------------------------------------------------
__global__ __launch_bounds__(256, 2) void gemm128(
    const unsigned short* __restrict__ A, const unsigned short* __restrict__ W,
    float* __restrict__ Cf, unsigned short* __restrict__ Cb,
    int M, int N, int K)
{
    __shared__ alignas(16) unsigned short As[6][64 * 32];    // 24 KB
    __shared__ alignas(16) unsigned short Bs[6][128 * 32];   // 48 KB

    int lane = threadIdx.x & 63;
    int w = threadIdx.x >> 6;
    int l15 = lane & 15, quad = lane >> 4;

    int tiles_n = N >> 7;
    int bid = (int)blockIdx.x;
    int nb = (int)gridDim.x;
    int lb = bid;
    if ((nb & 7) == 0) {                 // bijective XCD-chunk swizzle
        int c = nb >> 3;
        lb = (bid & 7) * c + (bid >> 3);
    }
    int mt0 = lb / tiles_n;
    int nt0 = lb - mt0 * tiles_n;

    size_t goffA;
    {
        int s = w * 64 + lane;
        int row = s >> 2, spos = s & 3;
        int kblk = spos ^ ((row >> 1) & 3);
        goffA = (size_t)(mt0 * 64 + row) * K + kblk * 8;
    }
    size_t goffB[2];
    #pragma unroll
    for (int is = 0; is < 2; ++is) {
        int s = w * 128 + is * 64 + lane;
        int row = s >> 2, spos = s & 3;
        int kblk = spos ^ ((row >> 1) & 3);
        goffB[is] = (size_t)(nt0 * 128 + row) * K + kblk * 8;
    }

    int arow0 = (w >> 1) * 32;
    int brow0 = (w & 1) * 64;
    int aoff[2], boff[4];
    #pragma unroll
    for (int t = 0; t < 2; ++t) {
        int ra = arow0 + t * 16 + l15;
        aoff[t] = (ra * 4 + (quad ^ ((ra >> 1) & 3))) * 8;
    }
    #pragma unroll
    for (int j = 0; j < 4; ++j) {
        int rb = brow0 + j * 16 + l15;
        boff[j] = (rb * 4 + (quad ^ ((rb >> 1) & 3))) * 8;
    }

    f32x4 acc[2][4];
    #pragma unroll
    for (int i = 0; i < 2; ++i)
        #pragma unroll
        for (int j = 0; j < 4; ++j) acc[i][j] = (f32x4){0.f, 0.f, 0.f, 0.f};

    auto stage = [&](int s, int b) {
        int k0 = s * 32;
        gl_lds16(A + goffA + k0, &As[b][(w * 64) * 8]);
        gl_lds16(W + goffB[0] + k0, &Bs[b][(w * 128 + 0) * 8]);
        gl_lds16(W + goffB[1] + k0, &Bs[b][(w * 128 + 64) * 8]);
    };

    int nk = K >> 5;            // 32 slices (K=1024); nk even required
    int np = nk >> 1;           // 16 phases
    if (nk > 0) stage(0, 0);
    if (nk > 1) stage(1, 1);
    if (nk > 2) stage(2, 2);
    if (nk > 3) stage(3, 3);
    int cb = 0, sb = 4;
    for (int j = 0; j < np; ++j) {
        MEMFENCE();
        if (j + 1 < np) __builtin_amdgcn_s_waitcnt(WAIT_VM6);
        else            __builtin_amdgcn_s_waitcnt(WAIT_VM0);
        __builtin_amdgcn_s_barrier();
        MEMFENCE();
        int s0 = 2 * j + 4;
        if (s0 < nk)     stage(s0, sb);
        if (s0 + 1 < nk) stage(s0 + 1, sb + 1 == 6 ? 0 : sb + 1);
        sb += 2; if (sb >= 6) sb -= 6;

        #pragma unroll
        for (int half = 0; half < 2; ++half) {
            const unsigned short* Ab = &As[cb + half][0];
            const unsigned short* Bb = &Bs[cb + half][0];
            bf16x8 af[2], bf_[4];
            #pragma unroll
            for (int t = 0; t < 2; ++t) af[t]  = *(const bf16x8*)(Ab + aoff[t]);
            #pragma unroll
            for (int jj = 0; jj < 4; ++jj) bf_[jj] = *(const bf16x8*)(Bb + boff[jj]);
            __builtin_amdgcn_s_setprio(1);
            #pragma unroll
            for (int i2 = 0; i2 < 2; ++i2)
                #pragma unroll
                for (int jj = 0; jj < 4; ++jj)
                    acc[i2][jj] = __builtin_amdgcn_mfma_f32_16x16x32_bf16(af[i2], bf_[jj], acc[i2][jj], 0, 0, 0);
            __builtin_amdgcn_s_setprio(0);
        }
        cb += 2; if (cb >= 6) cb -= 6;
        MEMFENCE();
    }

    #pragma unroll
    for (int i = 0; i < 2; ++i) {
        int row0 = mt0 * 64 + arow0 + i * 16 + quad * 4;
        #pragma unroll
        for (int j = 0; j < 4; ++j) {
            int col = nt0 * 128 + brow0 + j * 16 + l15;
            if (Cf) {
                #pragma unroll
                for (int reg = 0; reg < 4; ++reg)
                    Cf[(size_t)(row0 + reg) * N + col] = acc[i][j][reg];
            } else {
                #pragma unroll
                for (int reg = 0; reg < 4; ++reg)
                    Cb[(size_t)(row0 + reg) * N + col] = f2b(acc[i][j][reg]);
            }
        }
    }
}

// ---------------------------------------------------------------------------
// QKV projection, tile 64x128, 2-slice phases + 6 slice buffers (R20 config).
// FUSED epilogues: nt0 0..7 = Q (rope+prescale), 8..9 = K (rope), 10..11 =
// V (transpose).  Staging pool aliased with Ex/T epilogue LDS.
// ---------------------------------------------------------------------------
#define QKVW (HIDDEN + 2 * NKV * HD)   // 1536
__global__ __launch_bounds__(256, 2) void gemmqkv(
    const unsigned short* __restrict__ A, const unsigned short* __restrict__ W,
    const int* __restrict__ pos,
    unsigned short* __restrict__ Qb, unsigned short* __restrict__ Kb,
    unsigned short* __restrict__ Vt)
{
    __shared__ alignas(16) char pool[73728];   // 72 KB
    unsigned short (*As)[64 * 32]  = (unsigned short (*)[64 * 32])(pool);           // 6 x 4 KB
    unsigned short (*Bs)[128 * 32] = (unsigned short (*)[128 * 32])(pool + 24576);  // 6 x 8 KB
    float (*Ex)[32][68] = (float (*)[32][68])(pool);     // 34.8 KB (epilogue alias)
    unsigned short* T = (unsigned short*)(pool);         // 16.6 KB (epilogue alias)

    int lane = threadIdx.x & 63;
    int w = threadIdx.x >> 6;
    int l15 = lane & 15, quad = lane >> 4;

    const int K = HIDDEN;
    int bid = (int)blockIdx.x;
    int lb = (bid & 7) * 96 + (bid >> 3);    // bijective: 768 = 8 * 96
    int mt0 = lb / 12;
    int nt0 = lb - mt0 * 12;

    size_t goffA;
    {
        int s = w * 64 + lane;
        int row = s >> 2, spos = s & 3;
        int kblk = spos ^ ((row >> 1) & 3);
        goffA = (size_t)(mt0 * 64 + row) * K + kblk * 8;
    }
    size_t goffB[2];
    #pragma unroll
    for (int is = 0; is < 2; ++is) {
        int s = w * 128 + is * 64 + lane;
        int row = s >> 2, spos = s & 3;
        int kblk = spos ^ ((row >> 1) & 3);
        goffB[is] = (size_t)(nt0 * 128 + row) * K + kblk * 8;
    }

    int arow0 = (w >> 1) * 32;
    int brow0 = (w & 1) * 64;
    int aoff[2], boff[4];
    #pragma unroll
    for (int t = 0; t < 2; ++t) {
        int ra = arow0 + t * 16 + l15;
        aoff[t] = (ra * 4 + (quad ^ ((ra >> 1) & 3))) * 8;
    }
    #pragma unroll
    for (int j = 0; j < 4; ++j) {
        int rb = brow0 + j * 16 + l15;
        boff[j] = (rb * 4 + (quad ^ ((rb >> 1) & 3))) * 8;
    }

    f32x4 acc[2][4];
    #pragma unroll
    for (int i = 0; i < 2; ++i)
        #pragma unroll
        for (int j = 0; j < 4; ++j) acc[i][j] = (f32x4){0.f, 0.f, 0.f, 0.f};

    auto stage = [&](int s, int b) {
        int k0 = s * 32;
        gl_lds16(A + goffA + k0, &As[b][(w * 64) * 8]);
        gl_lds16(W + goffB[0] + k0, &Bs[b][(w * 128 + 0) * 8]);
        gl_lds16(W + goffB[1] + k0, &Bs[b][(w * 128 + 64) * 8]);
    };

    stage(0, 0);
    stage(1, 1);
    stage(2, 2);
    stage(3, 3);
    int cb = 0, sb = 4;
    for (int j = 0; j < 16; ++j) {
        MEMFENCE();
        if (j < 15) __builtin_amdgcn_s_waitcnt(WAIT_VM6);
        else        __builtin_amdgcn_s_waitcnt(WAIT_VM0);
        __builtin_amdgcn_s_barrier();
        MEMFENCE();
        int s0 = 2 * j + 4;
        if (s0 < 32)     stage(s0, sb);
        if (s0 + 1 < 32) stage(s0 + 1, sb + 1 == 6 ? 0 : sb + 1);
        sb += 2; if (sb >= 6) sb -= 6;

        #pragma unroll
        for (int half = 0; half < 2; ++half) {
            const unsigned short* Ab = &As[cb + half][0];
            const unsigned short* Bb = &Bs[cb + half][0];
            bf16x8 af[2], bf_[4];
            #pragma unroll
            for (int t = 0; t < 2; ++t) af[t]  = *(const bf16x8*)(Ab + aoff[t]);
            #pragma unroll
            for (int jj = 0; jj < 4; ++jj) bf_[jj] = *(const bf16x8*)(Bb + boff[jj]);
            __builtin_amdgcn_s_setprio(1);
            #pragma unroll
            for (int i2 = 0; i2 < 2; ++i2)
                #pragma unroll
                for (int jj = 0; jj < 4; ++jj)
                    acc[i2][jj] = __builtin_amdgcn_mfma_f32_16x16x32_bf16(af[i2], bf_[jj], acc[i2][jj], 0, 0, 0);
            __builtin_amdgcn_s_setprio(0);
        }
        cb += 2; if (cb >= 6) cb -= 6;
        MEMFENCE();
    }

    if (nt0 >= 10) {
        // ---- V: bf16 -> LDS tile [64 s][130 d-stride] -> transposed Vt
        int kv = nt0 - 10;
        __syncthreads();   // all K-loop LDS reads done before pool reuse
        #pragma unroll
        for (int i = 0; i < 2; ++i) {
            int srow = arow0 + i * 16 + quad * 4;
            #pragma unroll
            for (int j = 0; j < 4; ++j) {
                int d = brow0 + j * 16 + l15;
                #pragma unroll
                for (int reg = 0; reg < 4; ++reg)
                    T[(srow + reg) * 130 + d] = f2b(acc[i][j][reg]);
            }
        }
        __syncthreads();
        int tid = threadIdx.x;
        int dl = tid >> 4;               // 0..15
        int s4 = (tid & 15) * 4;         // s chunk (0..60)
        #pragma unroll
        for (int it = 0; it < 8; ++it) {
            int d = it * 16 + dl;
            u16x4 v4 = { T[(s4 + 0) * 130 + d], T[(s4 + 1) * 130 + d],
                         T[(s4 + 2) * 130 + d], T[(s4 + 3) * 130 + d] };
            *(u16x4*)(Vt + (size_t)kv * HD * S_LEN + (size_t)d * S_LEN
                      + mt0 * 64 + s4) = v4;
        }
        return;
    }

    // ---- Q/K: rope epilogue (one exchange round)
    bool isQ = (nt0 < 8);
    int kv = nt0 - 8;
    bool is64 = (pos[1] == 0) && (pos[3] == 0);
    const float qscale = 0.08838834764831843f;

    float invf[4];
    #pragma unroll
    for (int j = 0; j < 4; ++j) {
        int d6 = (brow0 + j * 16 + l15) & 63;
        invf[j] = exp2f(-(float)d6 * (13.287712379549449f / 64.0f));
    }

    __syncthreads();   // K-loop LDS reads done before pool reuse
    #pragma unroll
    for (int i = 0; i < 2; ++i)
        #pragma unroll
        for (int j = 0; j < 4; ++j)
            #pragma unroll
            for (int reg = 0; reg < 4; ++reg)
                Ex[w][i * 16 + quad * 4 + reg][j * 16 + l15] = acc[i][j][reg];
    __syncthreads();
    #pragma unroll
    for (int i = 0; i < 2; ++i) {
        #pragma unroll
        for (int reg = 0; reg < 4; ++reg) {
            int s = mt0 * 64 + arow0 + i * 16 + quad * 4 + reg;
            int pv_ = is64 ? pos[2 * s] : pos[s];
            float pf = (float)pv_;
            #pragma unroll
            for (int j = 0; j < 4; ++j) {
                float sn, cs;
                __sincosf(pf * invf[j], &sn, &cs);
                float a  = acc[i][j][reg];
                float pr = Ex[w ^ 1][i * 16 + quad * 4 + reg][j * 16 + l15];
                int d_local = brow0 + j * 16 + l15;
                float outv = (d_local < 64) ? (a * cs - pr * sn) : (a * cs + pr * sn);
                if (isQ) {
                    Qb[(size_t)s * HIDDEN + nt0 * HD + d_local] = f2b(outv * qscale);
                } else {
                    Kb[(size_t)kv * S_LEN * HD + (size_t)s * HD + d_local] = f2b(outv);
                }
            }
        }
    }
}

// ---------------------------------------------------------------------------
// Flash attention — frozen R20 config (best measured within 180.8 total).
// 64-key chunks, 16 q/wave, 512 blocks = 2/CU, register-direct P (S^T
// operand swap), single barrier/chunk, mirrored q-tile swizzle.
// Static schedule is provably makespan-65 (forced ramp+cap pairing);
// split-K alternative costs more in HBM partial traffic than it saves (R26).
// ---------------------------------------------------------------------------
__global__ __launch_bounds__(256, 2) void attn_coop(
    const unsigned short* __restrict__ Qb, const unsigned short* __restrict__ Kb,
    const unsigned short* __restrict__ Vt, unsigned short* __restrict__ Ctx)
{
    __shared__ alignas(16) unsigned short Klds[2][64 * 128];   // 32 KB
    __shared__ alignas(16) unsigned short Vlds[2][128 * 64];   // 32 KB

    int lane = threadIdx.x & 63;
    int w = threadIdx.x >> 6;
    int l15 = lane & 15, quad = lane >> 4;
    int h = blockIdx.y;
    int kv = h >> 2;                 // GROUPS = 4
    int qt = (h & 4) ? (63 - (int)blockIdx.x) : (int)blockIdx.x;
    int qb = qt * 64;
    int q16 = qb + w * 16;

    bf16x8 a_q[4];
    const unsigned short* qrow = Qb + (size_t)(q16 + l15) * HIDDEN + h * HD + quad * 8;
    #pragma unroll
    for (int st = 0; st < 4; ++st) a_q[st] = *(const bf16x8*)(qrow + st * 32);

    bf16x4 ones4;
    #pragma unroll
    for (int i = 0; i < 4; ++i) ones4[i] = (short)0x3F80;   // bf16 1.0

    int lo = qb - (WIN - 1); if (lo < 0) lo = 0; lo &= ~63;
    int nch = (qb + 64 - lo) >> 6;   // <= 33

    const unsigned short* gbase;
    unsigned short* ldsdst[2];
    int myoff[8];
    int jmul;
    if (w < 2) {
        gbase = Kb + (size_t)kv * S_LEN * HD;
        ldsdst[0] = &Klds[0][w * 8 * 512];
        ldsdst[1] = &Klds[1][w * 8 * 512];
        jmul = HD;
        #pragma unroll
        for (int tt = 0; tt < 8; ++tt) {
            int t = w * 8 + tt;
            int key  = t * 4 + (lane >> 4);
            int dblk = (lane & 15) ^ (key & 15);
            myoff[tt] = key * HD + dblk * 8;
        }
    } else {
        gbase = Vt + (size_t)kv * HD * S_LEN;
        ldsdst[0] = &Vlds[0][(w - 2) * 8 * 512];
        ldsdst[1] = &Vlds[1][(w - 2) * 8 * 512];
        jmul = 1;
        #pragma unroll
        for (int tt = 0; tt < 8; ++tt) {
            int t = (w - 2) * 8 + tt;
            int d    = t * 8 + (lane >> 3);
            int kblk = (lane & 7) ^ (d & 7);
            myoff[tt] = d * S_LEN + kblk * 8;
        }
    }

    auto issue = [&](int c) {
        int j0 = lo + c * 64;
        const unsigned short* src = gbase + (size_t)j0 * jmul;
        unsigned short* dst = ldsdst[c & 1];
        #pragma unroll
        for (int tt = 0; tt < 8; ++tt)
            gl_lds16(src + myoff[tt], dst + tt * 512);
    };

    f32x4 o[9];                      // o[0..7] = d-tiles, o[8] = row-sums l
    #pragma unroll
    for (int nd = 0; nd < 9; ++nd) o[nd] = (f32x4){0.f, 0.f, 0.f, 0.f};

    issue(0);

    for (int c = 0; c < nch; ++c) {
        int j0 = lo + c * 64;

        MEMFENCE();
        __builtin_amdgcn_s_waitcnt(WAIT_VM0);   // my slice of chunk c landed
        __builtin_amdgcn_s_barrier();           // chunk staged; buf[c-1] drained
        MEMFENCE();
        if (c + 1 < nch) issue(c + 1);

        const unsigned short* Kc = &Klds[c & 1][0];
        const unsigned short* Vc = &Vlds[c & 1][0];

        // ---- S^T tiles: [16 keys x 16 queries], A = K-frag, B = Q-frag
        f32x4 sc[4];
        #pragma unroll
        for (int t = 0; t < 4; ++t) {
            sc[t] = (f32x4){0.f, 0.f, 0.f, 0.f};
            int key = t * 16 + l15;
            #pragma unroll
            for (int st = 0; st < 4; ++st) {
                int off16 = key * 16 + ((st * 4 + quad) ^ (key & 15));
                bf16x8 ak = *(const bf16x8*)(Kc + off16 * 8);
                sc[t] = __builtin_amdgcn_mfma_f32_16x16x32_bf16(ak, a_q[st], sc[t], 0, 0, 0);
            }
        }

        // ---- P^T = exp(S^T): row = key (quad*4+reg), col = query (l15)
        float p[4][4];
        if (j0 + 63 <= q16 && j0 > q16 + 15 - WIN) {
            #pragma unroll
            for (int t = 0; t < 4; ++t)
                #pragma unroll
                for (int reg = 0; reg < 4; ++reg) p[t][reg] = __expf(sc[t][reg]);
        } else {
            int iq = q16 + l15;
            #pragma unroll
            for (int t = 0; t < 4; ++t) {
                #pragma unroll
                for (int reg = 0; reg < 4; ++reg) {
                    int key = j0 + t * 16 + quad * 4 + reg;
                    p[t][reg] = (key <= iq && key > iq - WIN) ? __expf(sc[t][reg]) : 0.f;
                }
            }
        }

        // ---- pack P into K=16 A-fragments — no LDS round-trip
        bf16x4 a_p[4];
        #pragma unroll
        for (int t = 0; t < 4; ++t) {
            a_p[t][0] = (short)f2b(p[t][0]);
            a_p[t][1] = (short)f2b(p[t][1]);
            a_p[t][2] = (short)f2b(p[t][2]);
            a_p[t][3] = (short)f2b(p[t][3]);
        }

        // ---- O += P@V, l += P@1 : 4 key-groups x (8 d-tiles + 1), K=16
        #pragma unroll
        for (int t = 0; t < 4; ++t) {
            #pragma unroll
            for (int nd = 0; nd < 8; ++nd) {
                int d = nd * 16 + l15;
                int kblk = t * 2 + (quad >> 1);
                int slot = d * 8 + (kblk ^ (d & 7));
                bf16x4 bv = *(const bf16x4*)(Vc + slot * 8 + (quad & 1) * 4);
                o[nd] = __builtin_amdgcn_mfma_f32_16x16x16bf16_1k(a_p[t], bv, o[nd], 0, 0, 0);
            }
            o[8] = __builtin_amdgcn_mfma_f32_16x16x16bf16_1k(a_p[t], ones4, o[8], 0, 0, 0);
        }
        MEMFENCE();
    }

    // ---- epilogue: ctx = O / l (O C-layout: col=l15=d, row=quad*4+reg=q)
    #pragma unroll
    for (int nd = 0; nd < 8; ++nd) {
        int d = nd * 16 + l15;
        #pragma unroll
        for (int reg = 0; reg < 4; ++reg) {
            int q = q16 + quad * 4 + reg;
            Ctx[(size_t)q * HIDDEN + h * HD + d] = f2b(o[nd][reg] / o[8][reg]);
        }
    }
}

// ---------------------------------------------------------------------------
extern "C" void kernel_launch(void* const* d_in, const int* in_sizes, int n_in,
                              void* d_out, int out_size, void* d_ws, size_t ws_size,
                              hipStream_t stream)
{
    const float* hidden = (const float*)d_in[0];
    const float* wq = (const float*)d_in[1];
    const float* wk = (const float*)d_in[2];
    const float* wv = (const float*)d_in[3];
    const float* wo = (const float*)d_in[4];
    const int* pos = (const int*)d_in[5];
    float* out = (float*)d_out;

    char* ws = (char*)d_ws;
    size_t off = 0;
    unsigned short* Hb   = (unsigned short*)(ws + off); off += (size_t)S_LEN * HIDDEN * 2;
    unsigned short* Wqkv = (unsigned short*)(ws + off); off += (size_t)QKVW * HIDDEN * 2;
    unsigned short* Wob  = (unsigned short*)(ws + off); off += (size_t)HIDDEN * HIDDEN * 2;
    unsigned short* Qb   = (unsigned short*)(ws + off); off += (size_t)S_LEN * HIDDEN * 2;
    unsigned short* Kb   = (unsigned short*)(ws + off); off += (size_t)S_LEN * NKV * HD * 2;
    unsigned short* Vt   = (unsigned short*)(ws + off); off += (size_t)S_LEN * NKV * HD * 2;
    unsigned short* Cb   = (unsigned short*)(ws + off); off += (size_t)S_LEN * HIDDEN * 2;

    const int n_h  = S_LEN * HIDDEN / 4;
    const int n_wq = HIDDEN * HIDDEN / 4;
    const int n_wk = NKV * HD * HIDDEN / 4;
    int tot4 = n_h + n_wq + 2 * n_wk + n_wq;
    cvt5<<<(tot4 + 255) / 256, 256, 0, stream>>>(
        hidden, Hb, n_h,
        wq, Wqkv, n_wq,
        wk, Wqkv + (size_t)HIDDEN * HIDDEN, n_wk,
        wv, Wqkv + (size_t)(HIDDEN + NKV * HD) * HIDDEN, n_wk,
        wo, Wob, n_wq);

    // fused QKV projection + RoPE + V-transpose, 64x128 tiles (768 blocks)
    gemmqkv<<<(S_LEN / 64) * 12, 256, 0, stream>>>(
        Hb, Wqkv, pos, Qb, Kb, Vt);

    // flash attention (512 blocks)
    attn_coop<<<dim3(S_LEN / 64, NH), 256, 0, stream>>>(Qb, Kb, Vt, Cb);

    // output projection -> fp32 d_out, 64x128 tiles (512 blocks)
    gemm128<<<(S_LEN / 64) * (HIDDEN / 128), 256, 0, stream>>>(
        Cb, Wob, out, nullptr, S_LEN, HIDDEN, HIDDEN);
}